// Round 2
// baseline (1040.355 us; speedup 1.0000x reference)
//
#include <hip/hip_runtime.h>

// ---------------------------------------------------------------------------
// AggregationGNN: edge embed (cat tables + RBF) -> gather src -> scatter-add
// at dst -> per-node 2-layer MLP (64->128->64, relu both).
//
// Layout decisions:
//  * Edge kernel: one wave (64 lanes) per edge; lane = output feature f.
//    Half-wave specialization: lane f<32 computes r_embed[d]; lane f>=32
//    computes p_embed[d]; the upper half gets the r-part via shfl_xor(32)
//    (rbf_b cancels in p-r). Halves exp+FMA work vs both-sides-per-lane.
//  * RBF trick: exp(-g(L-ck)^2) = exp(-gL^2) * exp(2L)^k * exp(-0.1k^2)
//    (g=10, ck=0.1k) -> 2 exps per lane + mul recurrence for k-powers,
//    Bk = exp(-0.1 k^2) folded in as compile-time literals.
//  * Per-edge scalars via readfirstlane -> SGPR -> s_load (e is wave-uniform
//    but the compiler can't prove it).
//  * Aggregation: atomicAdd f32 into d_out (zeroed via hipMemsetAsync);
//    device-scope by default on gfx950, coalesced 256B per wave.
//  * MLP: in-place on d_out; one thread per node; a[64]+acc[64] in VGPRs;
//    weights read via wave-uniform addresses -> scalar loads. W1 transposed
//    into d_ws (32KB) so per-j columns are contiguous for s_load batching.
// ---------------------------------------------------------------------------

#define CD 64
#define HID 128

__global__ __launch_bounds__(256) void transpose_w1_kernel(
    const float* __restrict__ W1,   // [64][128]
    float* __restrict__ W1t)        // [128][64]
{
    int idx = blockIdx.x * 256 + threadIdx.x;   // 8192 total
    if (idx >= 64 * 128) return;
    int i = idx >> 7;        // 0..63
    int j = idx & 127;       // 0..127
    W1t[j * 64 + i] = W1[i * 128 + j];
}

__global__ __launch_bounds__(256) void edge_kernel(
    const float* __restrict__ atom,     // [N][64]
    const int*   __restrict__ srcv, const int* __restrict__ dstv,
    const int*   __restrict__ rdv,  const int* __restrict__ rtv, const int* __restrict__ rrv,
    const int*   __restrict__ pdv,  const int* __restrict__ ptv, const int* __restrict__ prv,
    const float* __restrict__ rlenv, const float* __restrict__ plenv,
    const float* __restrict__ Edir,  // [8][32]
    const float* __restrict__ Etyp,  // [16][32]
    const float* __restrict__ Erng,  // [4][32]
    const float* __restrict__ rbfW,  // [20][32]
    const float* __restrict__ rbfB,  // [32]
    float* __restrict__ agg,         // [N][64], pre-zeroed
    int nE)
{
    int e = blockIdx.x * 4 + (threadIdx.x >> 6);
    if (e >= nE) return;
    e = __builtin_amdgcn_readfirstlane(e);   // wave-uniform -> SGPR -> s_loads

    int  f    = threadIdx.x & 63;    // output feature 0..63
    int  d    = f & 31;              // embed dim 0..31
    bool rhalf = (f < 32);           // lower half owns r, upper half owns p

    int   s  = srcv[e];
    int   t  = dstv[e];

    // my half's categorical indices and length
    int   id = rhalf ? rdv[e]  : pdv[e];
    int   it = rhalf ? rtv[e]  : ptv[e];
    int   ir = rhalf ? rrv[e]  : prv[e];
    float L  = rhalf ? rlenv[e] : plenv[e];

    float cat = Edir[id * 32 + d] + Etyp[it * 32 + d] + Erng[ir * 32 + d];

    // rbf[k] = A * T^k * Bk  (A = exp(-10 L^2), T = exp(2L), Bk = exp(-0.1 k^2))
    float A = expf(-10.f * L * L);
    float T = expf(2.f * L);

    const float Bk[20] = {
        1.0f,            9.0483742e-1f,  6.7032005e-1f,  4.0656966e-1f,
        2.0189652e-1f,   8.2084999e-2f,  2.7323722e-2f,  7.4465830e-3f,
        1.6615573e-3f,   3.0353914e-4f,  4.5399930e-5f,  5.5595310e-6f,
        5.5739037e-7f,   4.5753326e-8f,  3.0748799e-9f,  1.6918798e-10f,
        7.6217622e-12f,  2.8111856e-13f, 8.4885308e-15f, 2.0984571e-16f
    };

    float p = 1.f, acc = 0.f;
#pragma unroll
    for (int k = 0; k < 20; ++k) {
        acc = fmaf(p, Bk[k] * rbfW[k * 32 + d], acc);
        p *= T;
    }
    float mine = cat + A * acc;            // cat + rbf@W for my half (no bias)

    // upper half needs the lower half's (cat_r + dot_r); bias cancels in p-r
    float other = __shfl_xor(mine, 32, 64);
    float val = rhalf ? (mine + rbfB[d])        // r_embed
                      : (mine - other);         // p_embed - r_embed

    float msg = atom[(size_t)s * CD + f] + val;
    atomicAdd(&agg[(size_t)t * CD + f], msg);
}

__global__ __launch_bounds__(256) void mlp_kernel(
    const float* __restrict__ W1t,  // [128][64] transposed
    const float* __restrict__ b1,   // [128]
    const float* __restrict__ W2,   // [128][64]
    const float* __restrict__ b2,   // [64]
    float* __restrict__ io,         // [N][64]: in = agg, out = result (in-place)
    int nN)
{
    int n = blockIdx.x * 256 + threadIdx.x;
    if (n >= nN) return;
    float* row = io + (size_t)n * CD;

    float a[CD];
#pragma unroll
    for (int i = 0; i < CD / 4; ++i) {
        float4 v = reinterpret_cast<const float4*>(row)[i];
        a[4 * i + 0] = v.x; a[4 * i + 1] = v.y;
        a[4 * i + 2] = v.z; a[4 * i + 3] = v.w;
    }

    float acc[CD];
#pragma unroll
    for (int o = 0; o < CD; ++o) acc[o] = b2[o];

#pragma unroll 2
    for (int j = 0; j < HID; ++j) {
        const float* w1c = W1t + j * CD;   // contiguous column of W1 (uniform)
        // 4 partial chains to break the 64-deep FMA dependency
        float h0 = b1[j], h1 = 0.f, h2 = 0.f, h3 = 0.f;
#pragma unroll
        for (int i = 0; i < CD / 4; ++i) {
            h0 = fmaf(a[4 * i + 0], w1c[4 * i + 0], h0);
            h1 = fmaf(a[4 * i + 1], w1c[4 * i + 1], h1);
            h2 = fmaf(a[4 * i + 2], w1c[4 * i + 2], h2);
            h3 = fmaf(a[4 * i + 3], w1c[4 * i + 3], h3);
        }
        float h = fmaxf((h0 + h1) + (h2 + h3), 0.f);

        const float* w2r = W2 + j * CD;    // contiguous row of W2 (uniform)
#pragma unroll
        for (int o = 0; o < CD; ++o) acc[o] = fmaf(h, w2r[o], acc[o]);
    }

#pragma unroll
    for (int i = 0; i < CD / 4; ++i) {
        float4 v;
        v.x = fmaxf(acc[4 * i + 0], 0.f);
        v.y = fmaxf(acc[4 * i + 1], 0.f);
        v.z = fmaxf(acc[4 * i + 2], 0.f);
        v.w = fmaxf(acc[4 * i + 3], 0.f);
        reinterpret_cast<float4*>(row)[i] = v;
    }
}

extern "C" void kernel_launch(void* const* d_in, const int* in_sizes, int n_in,
                              void* d_out, int out_size, void* d_ws, size_t ws_size,
                              hipStream_t stream) {
    const float* atom  = (const float*)d_in[0];
    const int*   srcv  = (const int*)d_in[1];
    const int*   dstv  = (const int*)d_in[2];
    const int*   rdv   = (const int*)d_in[3];
    const int*   rtv   = (const int*)d_in[4];
    const int*   rrv   = (const int*)d_in[5];
    const int*   pdv   = (const int*)d_in[6];
    const int*   ptv   = (const int*)d_in[7];
    const int*   prv   = (const int*)d_in[8];
    const float* rlenv = (const float*)d_in[9];
    const float* plenv = (const float*)d_in[10];
    const float* Edir  = (const float*)d_in[11];
    const float* Etyp  = (const float*)d_in[12];
    const float* Erng  = (const float*)d_in[13];
    const float* rbfW  = (const float*)d_in[14];
    const float* rbfB  = (const float*)d_in[15];
    const float* W1    = (const float*)d_in[16];
    const float* b1    = (const float*)d_in[17];
    const float* W2    = (const float*)d_in[18];
    const float* b2    = (const float*)d_in[19];

    int nE = in_sizes[1];           // 1,000,000
    int nN = in_sizes[0] / CD;      // 500,000

    float* agg = (float*)d_out;     // aggregate directly into output buffer
    float* W1t = (float*)d_ws;      // 32 KB scratch for transposed W1

    // zero the aggregation buffer (harness poisons d_out each replay)
    hipMemsetAsync(agg, 0, (size_t)nN * CD * sizeof(float), stream);

    transpose_w1_kernel<<<32, 256, 0, stream>>>(W1, W1t);

    edge_kernel<<<(nE + 3) / 4, 256, 0, stream>>>(
        atom, srcv, dstv, rdv, rtv, rrv, pdv, ptv, prv, rlenv, plenv,
        Edir, Etyp, Erng, rbfW, rbfB, agg, nE);

    mlp_kernel<<<(nN + 255) / 256, 256, 0, stream>>>(W1t, b1, W2, b2, agg, nN);
}

// Round 5
// 865.355 us; speedup vs baseline: 1.2022x; 1.2022x over previous
//
#include <hip/hip_runtime.h>

// ---------------------------------------------------------------------------
// AggregationGNN: edge embed (cat tables + RBF) -> gather src -> scatter-add
// at dst -> per-node 2-layer MLP (64->128->64, relu both).
//
//  * Edge kernel: one wave per edge, lane = feature f; GRID-STRIDE chunked
//    loop (~123 edges/wave) so per-lane RBF weights (Bk[k]*rbfW[k][d]) and
//    rbf_b are hoisted into registers ONCE per wave. Half-wave split: lanes
//    f<32 compute r-side, f>=32 p-side; r-part crosses via shfl_xor(32)
//    (rbf_b cancels in p-r).
//  * RBF: exp(-10(L-0.1k)^2) = A * T^k * Bk, A=exp(-10L^2), T=exp(2L),
//    Bk=exp(-0.1k^2) folded into the hoisted weights; A folded into the
//    recurrence seed.
//  * Aggregation: f32 atomicAdd into d_out (device-scope default), 256B
//    coalesced per wave. d_out zeroed via hipMemsetAsync each call.
//  * MLP: in-place on d_out; one thread per node; a[]/acc[] in VGPRs;
//    weight rows are uniformly addressed (uniform j + SGPR base) so the
//    compiler emits s_load through the scalar cache. NOTE: do NOT use
//    address_space(4) pointers with float2 -- HIP_vector_type has no
//    AS4-source copy ctor (host compile fails). W1 transposed into d_ws.
// ---------------------------------------------------------------------------

#define CD 64
#define HID 128

__global__ __launch_bounds__(256) void transpose_w1_kernel(
    const float* __restrict__ W1,   // [64][128]
    float* __restrict__ W1t)        // [128][64]
{
    int idx = blockIdx.x * 256 + threadIdx.x;   // 8192 total
    if (idx >= 64 * 128) return;
    int i = idx >> 7;        // 0..63
    int j = idx & 127;       // 0..127
    W1t[j * 64 + i] = W1[i * 128 + j];
}

__global__ __launch_bounds__(256) void edge_kernel(
    const float* __restrict__ atom,     // [N][64]
    const int*   __restrict__ srcv, const int* __restrict__ dstv,
    const int*   __restrict__ rdv,  const int* __restrict__ rtv, const int* __restrict__ rrv,
    const int*   __restrict__ pdv,  const int* __restrict__ ptv, const int* __restrict__ prv,
    const float* __restrict__ rlenv, const float* __restrict__ plenv,
    const float* __restrict__ Edir,  // [8][32]
    const float* __restrict__ Etyp,  // [16][32]
    const float* __restrict__ Erng,  // [4][32]
    const float* __restrict__ rbfW,  // [20][32]
    const float* __restrict__ rbfB,  // [32]
    float* __restrict__ agg,         // [N][64], pre-zeroed
    int nE)
{
    int wid = __builtin_amdgcn_readfirstlane(blockIdx.x * 4 + (threadIdx.x >> 6));
    int nw  = gridDim.x * 4;         // waves in grid
    int f   = threadIdx.x & 63;      // output feature 0..63
    int d   = f & 31;                // embed dim 0..31
    bool rhalf = (f < 32);

    const float Bk[20] = {
        1.0f,            9.0483742e-1f,  6.7032005e-1f,  4.0656966e-1f,
        2.0189652e-1f,   8.2084999e-2f,  2.7323722e-2f,  7.4465830e-3f,
        1.6615573e-3f,   3.0353914e-4f,  4.5399930e-5f,  5.5595310e-6f,
        5.5739037e-7f,   4.5753326e-8f,  3.0748799e-9f,  1.6918798e-10f,
        7.6217622e-12f,  2.8111856e-13f, 8.4885308e-15f, 2.0984571e-16f
    };

    // hoisted per-lane RBF weights (even/odd k pairs) + bias — reused ~123x
    float wkx[10], wky[10];
#pragma unroll
    for (int m = 0; m < 10; ++m) {
        wkx[m] = Bk[2 * m]     * rbfW[(2 * m) * 32 + d];
        wky[m] = Bk[2 * m + 1] * rbfW[(2 * m + 1) * 32 + d];
    }
    float bias = rbfB[d];

    int per = (nE + nw - 1) / nw;    // contiguous chunk per wave
    int beg = wid * per;
    int end = beg + per; if (end > nE) end = nE;

    for (int e = beg; e < end; ++e) {
        int   s  = srcv[e];
        int   t  = dstv[e];
        int   id = rhalf ? rdv[e]   : pdv[e];
        int   it = rhalf ? rtv[e]   : ptv[e];
        int   ir = rhalf ? rrv[e]   : prv[e];
        float L  = rhalf ? rlenv[e] : plenv[e];

        float cat = Edir[id * 32 + d] + Etyp[it * 32 + d] + Erng[ir * 32 + d];

        float A  = __expf(-10.f * L * L);
        float T  = __expf(2.f * L);
        float T2 = T * T;
        float px = A, py = A * T;     // A folded into the recurrence seed
        float ax = 0.f, ay = 0.f;
#pragma unroll
        for (int m = 0; m < 10; ++m) {
            ax = fmaf(px, wkx[m], ax);
            ay = fmaf(py, wky[m], ay);
            px *= T2;
            py *= T2;
        }
        float mine = cat + ax + ay;           // my half's cat + rbf@W (no bias)

        float other = __shfl_xor(mine, 32);   // lower half's value to upper
        float val = rhalf ? (mine + bias)     // r_embed
                          : (mine - other);   // p_embed - r_embed (bias cancels)

        float msg = atom[(size_t)s * CD + f] + val;
        atomicAdd(&agg[(size_t)t * CD + f], msg);
    }
}

__global__ __launch_bounds__(256) void mlp_kernel(
    const float* __restrict__ W1t,  // [128][64] transposed
    const float* __restrict__ b1,   // [128]
    const float* __restrict__ W2,   // [128][64]
    const float* __restrict__ b2,   // [64]
    float* __restrict__ io,         // [N][64]: in = agg, out = result (in-place)
    int nN)
{
    int n = blockIdx.x * 256 + threadIdx.x;
    if (n >= nN) return;
    float* row = io + (size_t)n * CD;

    float a[CD];
#pragma unroll
    for (int i = 0; i < CD / 4; ++i) {
        float4 v = reinterpret_cast<const float4*>(row)[i];
        a[4 * i + 0] = v.x; a[4 * i + 1] = v.y;
        a[4 * i + 2] = v.z; a[4 * i + 3] = v.w;
    }

    float acc[CD];
#pragma unroll
    for (int o = 0; o < CD; ++o) acc[o] = b2[o];

#pragma unroll 2
    for (int j = 0; j < HID; ++j) {
        const float* w1 = W1t + (size_t)j * CD;   // uniform address -> s_load
        float h0 = b1[j], h1 = 0.f, h2 = 0.f, h3 = 0.f;
#pragma unroll
        for (int i = 0; i < CD / 4; ++i) {
            h0 = fmaf(a[4 * i + 0], w1[4 * i + 0], h0);
            h1 = fmaf(a[4 * i + 1], w1[4 * i + 1], h1);
            h2 = fmaf(a[4 * i + 2], w1[4 * i + 2], h2);
            h3 = fmaf(a[4 * i + 3], w1[4 * i + 3], h3);
        }
        float h = fmaxf((h0 + h1) + (h2 + h3), 0.f);

        const float* w2 = W2 + (size_t)j * CD;    // uniform address -> s_load
#pragma unroll
        for (int o = 0; o < CD; ++o) acc[o] = fmaf(h, w2[o], acc[o]);
    }

#pragma unroll
    for (int i = 0; i < CD / 4; ++i) {
        float4 v;
        v.x = fmaxf(acc[4 * i + 0], 0.f);
        v.y = fmaxf(acc[4 * i + 1], 0.f);
        v.z = fmaxf(acc[4 * i + 2], 0.f);
        v.w = fmaxf(acc[4 * i + 3], 0.f);
        reinterpret_cast<float4*>(row)[i] = v;
    }
}

extern "C" void kernel_launch(void* const* d_in, const int* in_sizes, int n_in,
                              void* d_out, int out_size, void* d_ws, size_t ws_size,
                              hipStream_t stream) {
    const float* atom  = (const float*)d_in[0];
    const int*   srcv  = (const int*)d_in[1];
    const int*   dstv  = (const int*)d_in[2];
    const int*   rdv   = (const int*)d_in[3];
    const int*   rtv   = (const int*)d_in[4];
    const int*   rrv   = (const int*)d_in[5];
    const int*   pdv   = (const int*)d_in[6];
    const int*   ptv   = (const int*)d_in[7];
    const int*   prv   = (const int*)d_in[8];
    const float* rlenv = (const float*)d_in[9];
    const float* plenv = (const float*)d_in[10];
    const float* Edir  = (const float*)d_in[11];
    const float* Etyp  = (const float*)d_in[12];
    const float* Erng  = (const float*)d_in[13];
    const float* rbfW  = (const float*)d_in[14];
    const float* rbfB  = (const float*)d_in[15];
    const float* W1    = (const float*)d_in[16];
    const float* b1    = (const float*)d_in[17];
    const float* W2    = (const float*)d_in[18];
    const float* b2    = (const float*)d_in[19];

    int nE = in_sizes[1];           // 1,000,000
    int nN = in_sizes[0] / CD;      // 500,000

    float* agg = (float*)d_out;     // aggregate directly into output buffer
    float* W1t = (float*)d_ws;      // 32 KB scratch for transposed W1

    // zero the aggregation buffer (harness poisons d_out each replay)
    (void)hipMemsetAsync(agg, 0, (size_t)nN * CD * sizeof(float), stream);

    transpose_w1_kernel<<<32, 256, 0, stream>>>(W1, W1t);

    // 2048 blocks x 4 waves = 8192 waves; ~123 contiguous edges per wave
    edge_kernel<<<2048, 256, 0, stream>>>(
        atom, srcv, dstv, rdv, rtv, rrv, pdv, ptv, prv, rlenv, plenv,
        Edir, Etyp, Erng, rbfW, rbfB, agg, nE);

    mlp_kernel<<<(nN + 255) / 256, 256, 0, stream>>>(W1t, b1, W2, b2, agg, nN);
}